// Round 1
// baseline (1806.347 us; speedup 1.0000x reference)
//
#include <hip/hip_runtime.h>
#include <cstdint>
#include <cstddef>

#define B_DIM 2048
#define I_DIM 20000
#define D_DIM 512
#define H_DIM 1024  // 2*D

typedef __bf16 bf16x8 __attribute__((ext_vector_type(8)));
typedef float f32x4 __attribute__((ext_vector_type(4)));
typedef unsigned short ushort8v __attribute__((ext_vector_type(8)));

__device__ __forceinline__ unsigned short f2bf(float f) {
  union { float f; unsigned u; } v; v.f = f;
  unsigned u = v.u;
  u += 0x7fffu + ((u >> 16) & 1u);   // RNE (inputs are finite)
  return (unsigned short)(u >> 16);
}
__device__ __forceinline__ float bf2f(unsigned short h) {
  union { unsigned u; float f; } v; v.u = ((unsigned)h) << 16;
  return v.f;
}

// ---------------------------------------------------------------------------
// noisy likes -> bf16 :  out = mask ? 0 : likes
__global__ void make_noisy_kernel(const float* __restrict__ likes,
                                  const int* __restrict__ mask,
                                  unsigned short* __restrict__ out, int n4) {
  int idx = blockIdx.x * blockDim.x + threadIdx.x;
  if (idx >= n4) return;
  float4 L = ((const float4*)likes)[idx];
  int4 M = ((const int4*)mask)[idx];
  unsigned short o0 = M.x ? (unsigned short)0 : f2bf(L.x);
  unsigned short o1 = M.y ? (unsigned short)0 : f2bf(L.y);
  unsigned short o2 = M.z ? (unsigned short)0 : f2bf(L.z);
  unsigned short o3 = M.w ? (unsigned short)0 : f2bf(L.w);
  ushort2 a; a.x = o0; a.y = o1;
  ushort2 b; b.x = o2; b.y = o3;
  ((ushort2*)out)[idx * 2] = a;
  ((ushort2*)out)[idx * 2 + 1] = b;
}

// ---------------------------------------------------------------------------
// transpose f32 [R,C] -> bf16 [C,R]   (all dims multiples of 32 here)
__global__ void transpose_to_bf16(const float* __restrict__ in,
                                  unsigned short* __restrict__ out, int R, int C) {
  __shared__ unsigned short tile[32][33];
  int c0 = blockIdx.x * 32, r0 = blockIdx.y * 32;
  int tx = threadIdx.x, ty = threadIdx.y;  // 32 x 8
#pragma unroll
  for (int i = 0; i < 4; i++) {
    int r = r0 + ty + i * 8;
    tile[ty + i * 8][tx] = f2bf(in[(size_t)r * C + c0 + tx]);
  }
  __syncthreads();
#pragma unroll
  for (int i = 0; i < 4; i++) {
    int c = c0 + ty + i * 8;
    out[(size_t)c * R + r0 + tx] = tile[tx][ty + i * 8];
  }
}

// ---------------------------------------------------------------------------
// popular = mean over rows of likes [B, I]
__global__ void popular_kernel(const float* __restrict__ likes,
                               float* __restrict__ pop, int rows_per) {
  int i = blockIdx.x * 256 + threadIdx.x;
  if (i >= I_DIM) return;
  int r0 = blockIdx.y * rows_per;
  float s = 0.f;
  for (int r = 0; r < rows_per; ++r) s += likes[(size_t)(r0 + r) * I_DIM + i];
  atomicAdd(&pop[i], s * (1.0f / B_DIM));
}

// ---------------------------------------------------------------------------
// L2-normalize rows of embed (bf16 [B, D]) -> normed (bf16)
__global__ void l2norm_kernel(const unsigned short* __restrict__ embed,
                              unsigned short* __restrict__ normed) {
  int row = blockIdx.x * 4 + (threadIdx.x >> 6);
  int lane = threadIdx.x & 63;
  const unsigned short* e = embed + (size_t)row * D_DIM;
  float v[8];
  float ss = 0.f;
#pragma unroll
  for (int j = 0; j < 8; j++) { v[j] = bf2f(e[lane + j * 64]); ss += v[j] * v[j]; }
#pragma unroll
  for (int o = 32; o > 0; o >>= 1) ss += __shfl_xor(ss, o, 64);
  float s = rsqrtf(fmaxf(ss, 1e-12f));
  unsigned short* nr = normed + (size_t)row * D_DIM;
#pragma unroll
  for (int j = 0; j < 8; j++) nr[lane + j * 64] = f2bf(v[j] * s);
}

// ---------------------------------------------------------------------------
// C[M,N] = act( A[M,K] @ BT[N,K]^T + bias )
// ACT: 0=none 1=relu 2=sigmoid 3=negate.  OUT_BF16: write bf16 (ws) else f32.
// M, K multiples of 64/32; N arbitrary (guarded). 64x64 tile, 4 waves.
template <int ACT, bool OUT_BF16>
__global__ __launch_bounds__(256) void gemm_bt(
    const unsigned short* __restrict__ A, const unsigned short* __restrict__ BT,
    const float* __restrict__ bias, void* __restrict__ Cout,
    int M, int N, int K, int lda, int ldb, int ldc) {
  __shared__ unsigned short As[64][40];  // +8 pad: stride 80B, 2-way max (free)
  __shared__ unsigned short Bs[64][40];
  const int n0 = blockIdx.x * 64;
  const int m0 = blockIdx.y * 64;
  const int t = threadIdx.x;
  const int lane = t & 63;
  const int wv = t >> 6;
  const int wm = (wv >> 1) * 32;
  const int wn = (wv & 1) * 32;
  const int quad = lane >> 4;
  const int tc = lane & 15;
  const int sr = t >> 2;         // staging row 0..63
  const int sk = (t & 3) * 8;    // staging k offset {0,8,16,24}

  f32x4 acc[2][2];
#pragma unroll
  for (int i = 0; i < 2; i++)
#pragma unroll
    for (int j = 0; j < 2; j++) acc[i][j] = (f32x4){0.f, 0.f, 0.f, 0.f};

  for (int kt = 0; kt < K; kt += 32) {
    __syncthreads();
    // stage A tile (M always full)
    *(ushort8v*)&As[sr][sk] =
        *(const ushort8v*)(A + (size_t)(m0 + sr) * lda + kt + sk);
    // stage B tile with N guard
    {
      int n = n0 + sr;
      ushort8v v = {0, 0, 0, 0, 0, 0, 0, 0};
      if (n < N) v = *(const ushort8v*)(BT + (size_t)n * ldb + kt + sk);
      *(ushort8v*)&Bs[sr][sk] = v;
    }
    __syncthreads();
    bf16x8 a0 = *(const bf16x8*)&As[wm + tc][quad * 8];
    bf16x8 a1 = *(const bf16x8*)&As[wm + 16 + tc][quad * 8];
    bf16x8 b0 = *(const bf16x8*)&Bs[wn + tc][quad * 8];
    bf16x8 b1 = *(const bf16x8*)&Bs[wn + 16 + tc][quad * 8];
    acc[0][0] = __builtin_amdgcn_mfma_f32_16x16x32_bf16(a0, b0, acc[0][0], 0, 0, 0);
    acc[0][1] = __builtin_amdgcn_mfma_f32_16x16x32_bf16(a0, b1, acc[0][1], 0, 0, 0);
    acc[1][0] = __builtin_amdgcn_mfma_f32_16x16x32_bf16(a1, b0, acc[1][0], 0, 0, 0);
    acc[1][1] = __builtin_amdgcn_mfma_f32_16x16x32_bf16(a1, b1, acc[1][1], 0, 0, 0);
  }

#pragma unroll
  for (int ni = 0; ni < 2; ni++) {
    int col = n0 + wn + ni * 16 + tc;
    if (col >= N) continue;
    float bv = bias ? bias[col] : 0.f;
#pragma unroll
    for (int mi = 0; mi < 2; mi++) {
#pragma unroll
      for (int r = 0; r < 4; r++) {
        int row = m0 + wm + mi * 16 + quad * 4 + r;
        float v = acc[mi][ni][r] + bv;
        if (ACT == 1) v = v > 0.f ? v : 0.f;
        else if (ACT == 2) v = 1.f / (1.f + __expf(-v));
        else if (ACT == 3) v = -v;
        if (OUT_BF16)
          ((unsigned short*)Cout)[(size_t)row * ldc + col] = f2bf(v);
        else
          ((float*)Cout)[(size_t)row * ldc + col] = v;
      }
    }
  }
}

// ---------------------------------------------------------------------------
extern "C" void kernel_launch(void* const* d_in, const int* in_sizes, int n_in,
                              void* d_out, int out_size, void* d_ws, size_t ws_size,
                              hipStream_t stream) {
  const float* likes = (const float*)d_in[1];
  const int* mask = (const int*)d_in[2];
  const float* enc_w1 = (const float*)d_in[3];
  const float* enc_b1 = (const float*)d_in[4];
  const float* enc_w2 = (const float*)d_in[5];
  const float* enc_b2 = (const float*)d_in[6];
  const float* lk_w1 = (const float*)d_in[7];
  const float* lk_b1 = (const float*)d_in[8];
  const float* lk_w2 = (const float*)d_in[9];
  const float* lk_b2 = (const float*)d_in[10];
  const float* rc_w1 = (const float*)d_in[11];
  const float* rc_b1 = (const float*)d_in[12];
  const float* rc_w2 = (const float*)d_in[13];
  const float* rc_b2 = (const float*)d_in[14];

  float* out_likes = (float*)d_out;
  float* out_sim = out_likes + (size_t)B_DIM * I_DIM;
  float* out_rec = out_sim + (size_t)B_DIM * B_DIM;
  float* out_pop = out_rec + (size_t)B_DIM * I_DIM;

  unsigned short* ws = (unsigned short*)d_ws;
  unsigned short* A_noisy = ws;                   // 40,960,000 elems
  unsigned short* W1T = A_noisy + 40960000;       // 20,480,000
  unsigned short* W2T = W1T + 20480000;           //    524,288
  unsigned short* LK1T = W2T + 524288;            //    524,288
  unsigned short* RC1T = LK1T + 524288;           //    524,288
  unsigned short* h1 = RC1T + 524288;             //  2,097,152
  unsigned short* embed = h1 + 2097152;           //  1,048,576
  unsigned short* hlk = embed + 1048576;          //  2,097,152
  unsigned short* hrc = hlk + 2097152;            //  2,097,152
  unsigned short* normed = hrc + 2097152;         //  1,048,576
  unsigned short* LK2T = A_noisy;                 // reuse (A_noisy dead after G1)
  unsigned short* RC2T = A_noisy + 20480000;

  // popular (exact in f32: dyadic partial sums)
  hipMemsetAsync(out_pop, 0, I_DIM * sizeof(float), stream);
  popular_kernel<<<dim3((I_DIM + 255) / 256, 16), 256, 0, stream>>>(likes, out_pop,
                                                                    B_DIM / 16);
  // noisy likes -> bf16
  make_noisy_kernel<<<(B_DIM * I_DIM / 4 + 255) / 256, 256, 0, stream>>>(
      likes, mask, A_noisy, B_DIM * I_DIM / 4);

  // encoder
  transpose_to_bf16<<<dim3(H_DIM / 32, I_DIM / 32), dim3(32, 8), 0, stream>>>(
      enc_w1, W1T, I_DIM, H_DIM);
  gemm_bt<1, true><<<dim3(H_DIM / 64, B_DIM / 64), 256, 0, stream>>>(
      A_noisy, W1T, enc_b1, h1, B_DIM, H_DIM, I_DIM, I_DIM, I_DIM, H_DIM);
  transpose_to_bf16<<<dim3(D_DIM / 32, H_DIM / 32), dim3(32, 8), 0, stream>>>(
      enc_w2, W2T, H_DIM, D_DIM);
  gemm_bt<1, true><<<dim3(D_DIM / 64, B_DIM / 64), 256, 0, stream>>>(
      h1, W2T, enc_b2, embed, B_DIM, D_DIM, H_DIM, H_DIM, H_DIM, D_DIM);

  // cosine-similarity gram
  l2norm_kernel<<<B_DIM / 4, 256, 0, stream>>>(embed, normed);
  gemm_bt<3, false><<<dim3(B_DIM / 64, B_DIM / 64), 256, 0, stream>>>(
      normed, normed, nullptr, out_sim, B_DIM, B_DIM, D_DIM, D_DIM, D_DIM, B_DIM);

  // likes head
  transpose_to_bf16<<<dim3(H_DIM / 32, D_DIM / 32), dim3(32, 8), 0, stream>>>(
      lk_w1, LK1T, D_DIM, H_DIM);
  gemm_bt<1, true><<<dim3(H_DIM / 64, B_DIM / 64), 256, 0, stream>>>(
      embed, LK1T, lk_b1, hlk, B_DIM, H_DIM, D_DIM, D_DIM, D_DIM, H_DIM);
  transpose_to_bf16<<<dim3(I_DIM / 32, H_DIM / 32), dim3(32, 8), 0, stream>>>(
      lk_w2, LK2T, H_DIM, I_DIM);
  gemm_bt<2, false><<<dim3((I_DIM + 63) / 64, B_DIM / 64), 256, 0, stream>>>(
      hlk, LK2T, lk_b2, out_likes, B_DIM, I_DIM, H_DIM, H_DIM, H_DIM, I_DIM);

  // rec head
  transpose_to_bf16<<<dim3(H_DIM / 32, D_DIM / 32), dim3(32, 8), 0, stream>>>(
      rc_w1, RC1T, D_DIM, H_DIM);
  gemm_bt<1, true><<<dim3(H_DIM / 64, B_DIM / 64), 256, 0, stream>>>(
      embed, RC1T, rc_b1, hrc, B_DIM, H_DIM, D_DIM, D_DIM, D_DIM, H_DIM);
  transpose_to_bf16<<<dim3(I_DIM / 32, H_DIM / 32), dim3(32, 8), 0, stream>>>(
      rc_w2, RC2T, H_DIM, I_DIM);
  gemm_bt<2, false><<<dim3((I_DIM + 63) / 64, B_DIM / 64), 256, 0, stream>>>(
      hrc, RC2T, rc_b2, out_rec, B_DIM, I_DIM, H_DIM, H_DIM, H_DIM, I_DIM);
}

// Round 2
// 1284.909 us; speedup vs baseline: 1.4058x; 1.4058x over previous
//
#include <hip/hip_runtime.h>
#include <cstdint>
#include <cstddef>

#define B_DIM 2048
#define I_DIM 20000
#define D_DIM 512
#define H_DIM 1024  // 2*D

typedef __bf16 bf16x8 __attribute__((ext_vector_type(8)));
typedef float f32x4 __attribute__((ext_vector_type(4)));

__device__ __forceinline__ unsigned short f2bf(float f) {
  union { float f; unsigned u; } v; v.f = f;
  unsigned u = v.u;
  u += 0x7fffu + ((u >> 16) & 1u);  // RNE (finite inputs)
  return (unsigned short)(u >> 16);
}
__device__ __forceinline__ float bf2f(unsigned short h) {
  union { unsigned u; float f; } v; v.u = ((unsigned)h) << 16;
  return v.f;
}

// async global->LDS, 16B per lane; lds dest = wave-uniform base + lane*16
__device__ __forceinline__ void glds16(const unsigned short* g, unsigned short* l) {
  __builtin_amdgcn_global_load_lds(
      (const __attribute__((address_space(1))) void*)g,
      (__attribute__((address_space(3))) void*)l, 16, 0, 0);
}

// ---------------------------------------------------------------------------
// Fused: noisy = mask ? 0 : likes (bf16), popular += colsum(likes)/B
// grid: (ceil(5000/256), B/64), 256 thr. Each thread: one float4 column group,
// 64 rows. Dyadic partials -> bit-exact popular.
__global__ void noisy_popular_kernel(const float* __restrict__ likes,
                                     const int* __restrict__ mask,
                                     unsigned short* __restrict__ noisy,
                                     float* __restrict__ pop) {
  int idx4 = blockIdx.x * 256 + threadIdx.x;  // float4 column index, < 5000
  if (idx4 >= I_DIM / 4) return;
  int r0 = blockIdx.y * 64;
  float4 s = make_float4(0.f, 0.f, 0.f, 0.f);
  for (int r = 0; r < 64; ++r) {
    size_t off = (size_t)(r0 + r) * (I_DIM / 4) + idx4;
    float4 L = ((const float4*)likes)[off];
    int4 M = ((const int4*)mask)[off];
    s.x += L.x; s.y += L.y; s.z += L.z; s.w += L.w;
    ushort4 o;
    o.x = M.x ? (unsigned short)0 : f2bf(L.x);
    o.y = M.y ? (unsigned short)0 : f2bf(L.y);
    o.z = M.z ? (unsigned short)0 : f2bf(L.z);
    o.w = M.w ? (unsigned short)0 : f2bf(L.w);
    ((ushort4*)noisy)[off] = o;
  }
  const float inv = 1.0f / B_DIM;
  atomicAdd(&pop[idx4 * 4 + 0], s.x * inv);
  atomicAdd(&pop[idx4 * 4 + 1], s.y * inv);
  atomicAdd(&pop[idx4 * 4 + 2], s.z * inv);
  atomicAdd(&pop[idx4 * 4 + 3], s.w * inv);
}

// ---------------------------------------------------------------------------
// transpose f32 [R,C] -> bf16 [C,R] (R,C multiples of 32)
__global__ void transpose_to_bf16(const float* __restrict__ in,
                                  unsigned short* __restrict__ out, int R, int C) {
  __shared__ unsigned short tile[32][33];
  int c0 = blockIdx.x * 32, r0 = blockIdx.y * 32;
  int tx = threadIdx.x, ty = threadIdx.y;  // 32 x 8
#pragma unroll
  for (int i = 0; i < 4; i++) {
    int r = r0 + ty + i * 8;
    tile[ty + i * 8][tx] = f2bf(in[(size_t)r * C + c0 + tx]);
  }
  __syncthreads();
#pragma unroll
  for (int i = 0; i < 4; i++) {
    int c = c0 + ty + i * 8;
    out[(size_t)c * R + r0 + tx] = tile[tx][ty + i * 8];
  }
}

// ---------------------------------------------------------------------------
__global__ void concat_bias_kernel(const float* __restrict__ a,
                                   const float* __restrict__ b,
                                   float* __restrict__ out) {
  int i = blockIdx.x * 256 + threadIdx.x;
  if (i < H_DIM) out[i] = a[i];
  else if (i < 2 * H_DIM) out[i] = b[i - H_DIM];
}

// ---------------------------------------------------------------------------
// h1 = bf16(relu(sum_z partial[z] + bias))   partial: [5][B][H] f32
__global__ void reduce_relu_kernel(const float* __restrict__ partial,
                                   const float* __restrict__ bias,
                                   unsigned short* __restrict__ h1) {
  int idx4 = blockIdx.x * 256 + threadIdx.x;  // float4 index over B*H/4
  const size_t slice = (size_t)B_DIM * H_DIM / 4;
  float4 s = ((const float4*)partial)[idx4];
#pragma unroll
  for (int z = 1; z < 5; z++) {
    float4 p = ((const float4*)partial)[z * slice + idx4];
    s.x += p.x; s.y += p.y; s.z += p.z; s.w += p.w;
  }
  float4 b = ((const float4*)bias)[idx4 & (H_DIM / 4 - 1)];
  ushort4 o;
  o.x = f2bf(fmaxf(s.x + b.x, 0.f));
  o.y = f2bf(fmaxf(s.y + b.y, 0.f));
  o.z = f2bf(fmaxf(s.z + b.z, 0.f));
  o.w = f2bf(fmaxf(s.w + b.w, 0.f));
  ((ushort4*)h1)[idx4] = o;
}

// ---------------------------------------------------------------------------
// L2-normalize rows of embed (bf16 [B, D]) -> normed (bf16)
__global__ void l2norm_kernel(const unsigned short* __restrict__ embed,
                              unsigned short* __restrict__ normed) {
  int row = blockIdx.x * 4 + (threadIdx.x >> 6);
  int lane = threadIdx.x & 63;
  const unsigned short* e = embed + (size_t)row * D_DIM;
  float v[8];
  float ss = 0.f;
#pragma unroll
  for (int j = 0; j < 8; j++) { v[j] = bf2f(e[lane + j * 64]); ss += v[j] * v[j]; }
#pragma unroll
  for (int o = 32; o > 0; o >>= 1) ss += __shfl_xor(ss, o, 64);
  float s = rsqrtf(fmaxf(ss, 1e-12f));
  unsigned short* nr = normed + (size_t)row * D_DIM;
#pragma unroll
  for (int j = 0; j < 8; j++) nr[lane + j * 64] = f2bf(v[j] * s);
}

// ---------------------------------------------------------------------------
// m97-structure GEMM: C[M,N] = act(A[M,K] @ BT[N,K]^T + bias)
// 128x128 tile, BK=32, 4 waves each 64x64 (4x4 16x16x32 mfma),
// global_load_lds width=16 staging, unpadded LDS [128][32].
// Requires: M % 128 == 0, kLen % 32 == 0, rows of A/BT 16B-aligned,
// BT physically padded to n-blocks of 128 rows (epilogue guards col<N).
// ACT: 0=none 1=relu 2=sigmoid 3=negate. OBF16: bf16 out else f32.
// k0 = blockIdx.z*kLen; f32 out offset by blockIdx.z*zStride (split-K).
template <int ACT, bool OBF16>
__global__ __launch_bounds__(256) void gemm128(
    const unsigned short* __restrict__ A, const unsigned short* __restrict__ BT,
    const float* __restrict__ bias, void* __restrict__ Cout,
    int N, int lda, int ldb, int ldc, int kLen, long long zStride) {
  __shared__ unsigned short As[128 * 32];
  __shared__ unsigned short Bs[128 * 32];
  const int n0 = blockIdx.x * 128;
  const int m0 = blockIdx.y * 128;
  const int t = threadIdx.x;
  const int lane = t & 63;
  const int wv = t >> 6;
  const int quad = lane >> 4;
  const int tc = lane & 15;
  const int wm = (wv >> 1) * 64;
  const int wn = (wv & 1) * 64;
  const int k0 = blockIdx.z * kLen;

  f32x4 acc[4][4];
#pragma unroll
  for (int i = 0; i < 4; i++)
#pragma unroll
    for (int j = 0; j < 4; j++) acc[i][j] = (f32x4){0.f, 0.f, 0.f, 0.f};

  // staging: wave wv covers rows [wv*32, wv*32+32); lane L -> row + L/4,
  // k-chunk (L&3)*8 elems; LDS dest = base + L*16B (matches [row][32] layout)
  const int srow = lane >> 2;
  const int skch = (lane & 3) * 8;
  const unsigned short* gA0 = A + (size_t)(m0 + wv * 32 + srow) * lda + k0 + skch;
  const unsigned short* gA1 = gA0 + (size_t)16 * lda;
  const unsigned short* gB0 = BT + (size_t)(n0 + wv * 32 + srow) * ldb + k0 + skch;
  const unsigned short* gB1 = gB0 + (size_t)16 * ldb;
  unsigned short* lA = As + wv * 1024;
  unsigned short* lB = Bs + wv * 1024;

  const int nIter = kLen >> 5;
  for (int it = 0; it < nIter; ++it) {
    __syncthreads();
    glds16(gA0, lA);
    glds16(gA1, lA + 512);
    glds16(gB0, lB);
    glds16(gB1, lB + 512);
    gA0 += 32; gA1 += 32; gB0 += 32; gB1 += 32;
    __syncthreads();
    bf16x8 a[4], b[4];
#pragma unroll
    for (int i = 0; i < 4; i++) {
      a[i] = *(const bf16x8*)&As[(wm + i * 16 + tc) * 32 + quad * 8];
      b[i] = *(const bf16x8*)&Bs[(wn + i * 16 + tc) * 32 + quad * 8];
    }
#pragma unroll
    for (int i = 0; i < 4; i++)
#pragma unroll
      for (int j = 0; j < 4; j++)
        acc[i][j] =
            __builtin_amdgcn_mfma_f32_16x16x32_bf16(a[i], b[j], acc[i][j], 0, 0, 0);
  }

  float* outF = (float*)Cout + (size_t)blockIdx.z * zStride;
  unsigned short* outH = (unsigned short*)Cout;
#pragma unroll
  for (int j = 0; j < 4; j++) {
    int col = n0 + wn + j * 16 + tc;
    if (col >= N) continue;
    float bv = bias ? bias[col] : 0.f;
#pragma unroll
    for (int i = 0; i < 4; i++) {
      int row0 = m0 + wm + i * 16 + quad * 4;
#pragma unroll
      for (int r = 0; r < 4; r++) {
        float v = acc[i][j][r] + bv;
        if (ACT == 1) v = fmaxf(v, 0.f);
        else if (ACT == 2) v = 1.f / (1.f + __expf(-v));
        else if (ACT == 3) v = -v;
        if (OBF16)
          outH[(size_t)(row0 + r) * ldc + col] = f2bf(v);
        else
          outF[(size_t)(row0 + r) * ldc + col] = v;
      }
    }
  }
}

// ---------------------------------------------------------------------------
extern "C" void kernel_launch(void* const* d_in, const int* in_sizes, int n_in,
                              void* d_out, int out_size, void* d_ws, size_t ws_size,
                              hipStream_t stream) {
  const float* likes = (const float*)d_in[1];
  const int* mask = (const int*)d_in[2];
  const float* enc_w1 = (const float*)d_in[3];
  const float* enc_b1 = (const float*)d_in[4];
  const float* enc_w2 = (const float*)d_in[5];
  const float* enc_b2 = (const float*)d_in[6];
  const float* lk_w1 = (const float*)d_in[7];
  const float* lk_b1 = (const float*)d_in[8];
  const float* lk_w2 = (const float*)d_in[9];
  const float* lk_b2 = (const float*)d_in[10];
  const float* rc_w1 = (const float*)d_in[11];
  const float* rc_b1 = (const float*)d_in[12];
  const float* rc_w2 = (const float*)d_in[13];
  const float* rc_b2 = (const float*)d_in[14];

  float* out_likes = (float*)d_out;
  float* out_sim = out_likes + (size_t)B_DIM * I_DIM;
  float* out_rec = out_sim + (size_t)B_DIM * B_DIM;
  float* out_pop = out_rec + (size_t)B_DIM * I_DIM;

  // ws layout (ushort units). A_noisy region is reused by LK2T/RC2T after G1.
  unsigned short* ws = (unsigned short*)d_ws;
  unsigned short* A_noisy = ws;                      // [0, 40,960,000)
  unsigned short* LK2T = ws;                         // 20096x1024 (padded rows)
  unsigned short* RC2T = ws + 20578304;              // 20096x1024
  unsigned short* W1T = ws + 41156608;               // 1024x20000
  unsigned short* W2T = W1T + 20480000;              // 512x1024
  unsigned short* W1catT = W2T + 524288;             // 2048x512
  float* bcat = (float*)(W1catT + 1048576);          // 2048 f32
  unsigned short* h1 = W1catT + 1048576 + 4096;      // 2048x1024
  unsigned short* hboth = h1 + 2097152;              // 2048x2048
  unsigned short* embed = hboth + 4194304;           // 2048x512
  unsigned short* normed = embed + 1048576;          // 2048x512
  // split-K partials live in d_out's out_rec region (written later by G6)
  float* partial = out_rec;                          // [5][2048][1024] f32

  // popular + noisy cast (fused; one pass over likes)
  hipMemsetAsync(out_pop, 0, I_DIM * sizeof(float), stream);
  noisy_popular_kernel<<<dim3((I_DIM / 4 + 255) / 256, B_DIM / 64), 256, 0,
                         stream>>>(likes, mask, A_noisy, out_pop);

  // ---- encoder layer 1: split-K=5 (K chunks of 4000), partials f32
  transpose_to_bf16<<<dim3(H_DIM / 32, I_DIM / 32), dim3(32, 8), 0, stream>>>(
      enc_w1, W1T, I_DIM, H_DIM);
  gemm128<0, false><<<dim3(H_DIM / 128, B_DIM / 128, 5), 256, 0, stream>>>(
      A_noisy, W1T, nullptr, partial, H_DIM, I_DIM, I_DIM, H_DIM, 4000,
      (long long)B_DIM * H_DIM);
  reduce_relu_kernel<<<B_DIM * H_DIM / 4 / 256, 256, 0, stream>>>(partial, enc_b1,
                                                                  h1);

  // ---- encoder layer 2
  transpose_to_bf16<<<dim3(D_DIM / 32, H_DIM / 32), dim3(32, 8), 0, stream>>>(
      enc_w2, W2T, H_DIM, D_DIM);
  gemm128<1, true><<<dim3(D_DIM / 128, B_DIM / 128, 1), 256, 0, stream>>>(
      h1, W2T, enc_b2, embed, D_DIM, H_DIM, H_DIM, D_DIM, H_DIM, 0);

  // ---- cosine-similarity gram
  l2norm_kernel<<<B_DIM / 4, 256, 0, stream>>>(embed, normed);
  gemm128<3, false><<<dim3(B_DIM / 128, B_DIM / 128, 1), 256, 0, stream>>>(
      normed, normed, nullptr, out_sim, B_DIM, D_DIM, D_DIM, B_DIM, D_DIM, 0);

  // ---- heads layer 1 (fused lk|rc): N = 2048
  concat_bias_kernel<<<2 * H_DIM / 256, 256, 0, stream>>>(lk_b1, rc_b1, bcat);
  transpose_to_bf16<<<dim3(H_DIM / 32, D_DIM / 32), dim3(32, 8), 0, stream>>>(
      lk_w1, W1catT, D_DIM, H_DIM);
  transpose_to_bf16<<<dim3(H_DIM / 32, D_DIM / 32), dim3(32, 8), 0, stream>>>(
      rc_w1, W1catT + (size_t)H_DIM * D_DIM, D_DIM, H_DIM);
  gemm128<1, true><<<dim3(2 * H_DIM / 128, B_DIM / 128, 1), 256, 0, stream>>>(
      embed, W1catT, bcat, hboth, 2 * H_DIM, D_DIM, D_DIM, 2 * H_DIM, D_DIM, 0);

  // ---- heads layer 2 (A_noisy region now dead -> LK2T/RC2T)
  transpose_to_bf16<<<dim3(I_DIM / 32, H_DIM / 32), dim3(32, 8), 0, stream>>>(
      lk_w2, LK2T, H_DIM, I_DIM);
  transpose_to_bf16<<<dim3(I_DIM / 32, H_DIM / 32), dim3(32, 8), 0, stream>>>(
      rc_w2, RC2T, H_DIM, I_DIM);
  gemm128<2, false><<<dim3((I_DIM + 127) / 128, B_DIM / 128, 1), 256, 0, stream>>>(
      hboth, LK2T, lk_b2, out_likes, I_DIM, 2 * H_DIM, H_DIM, I_DIM, H_DIM, 0);
  gemm128<2, false><<<dim3((I_DIM + 127) / 128, B_DIM / 128, 1), 256, 0, stream>>>(
      hboth + H_DIM, RC2T, rc_b2, out_rec, I_DIM, 2 * H_DIM, H_DIM, I_DIM, H_DIM, 0);
}